// Round 6
// baseline (868.365 us; speedup 1.0000x reference)
//
#include <hip/hip_runtime.h>
#include <hip/hip_bf16.h>
#include <hip/hip_fp16.h>

#define RN 4096
#define EN 131072
#define TN 1536
#define T2 768            // sample-pairs per row
#define SP 1040           // padded row stride in pairs
#define PADP 257          // front wrap-replica pairs
#define PN 256
#define NBOUNCE 12
#define NCHUNK 3
#define CP 256            // pairs per chunk (4 per lane x 64 lanes)
// np.float32(np.log(1e-3))
#define LOG_GAMMA -6.90775528f
#define INV_SR (1.0f / 16000.0f)

#define rfl(x) __builtin_amdgcn_readfirstlane(x)

// ---------------- CSR build ----------------

__global__ void hist_kernel(const int* __restrict__ row, int* __restrict__ cnt) {
    int e = blockIdx.x * blockDim.x + threadIdx.x;
    if (e < EN) atomicAdd(&cnt[row[e]], 1);
}

// single block, 1024 threads: exclusive scan of even-rounded counts.
// Row r's region is [off[r], off[r]+cnt[r]) real + pad slot to even length.
__global__ void scan_kernel(const int* __restrict__ cnt, int* __restrict__ off,
                            int* __restrict__ cursor) {
    __shared__ int part[1024];
    int tid = threadIdx.x;
    int v0 = cnt[tid * 4 + 0], v1 = cnt[tid * 4 + 1];
    int v2 = cnt[tid * 4 + 2], v3 = cnt[tid * 4 + 3];
    int p0 = (v0 + 1) & ~1, p1 = (v1 + 1) & ~1, p2 = (v2 + 1) & ~1, p3 = (v3 + 1) & ~1;
    part[tid] = p0 + p1 + p2 + p3;
    __syncthreads();
    for (int ofs = 1; ofs < 1024; ofs <<= 1) {
        int x = (tid >= ofs) ? part[tid - ofs] : 0;
        __syncthreads();
        part[tid] += x;
        __syncthreads();
    }
    int excl = (tid == 0) ? 0 : part[tid - 1];
    int o0 = excl, o1 = o0 + p0, o2 = o1 + p1, o3 = o2 + p2;
    off[tid * 4 + 0] = o0; cursor[tid * 4 + 0] = o0;
    off[tid * 4 + 1] = o1; cursor[tid * 4 + 1] = o1;
    off[tid * 4 + 2] = o2; cursor[tid * 4 + 2] = o2;
    off[tid * 4 + 3] = o3; cursor[tid * 4 + 3] = o3;
    if (tid == 1023) off[RN] = o3 + p3;
}

// per edge: kernel value + precomputed relative byte offset into the padded layout.
// md.x = ((col*SP + PADP - dpair) << 2) | (delay & 1),  md.y = bits(kern)
__global__ void scatter_kernel(const int* __restrict__ row, const int* __restrict__ col,
                               const int* __restrict__ rid, const int* __restrict__ delay,
                               const float* __restrict__ basis,
                               const float* __restrict__ absorption,
                               const float* __restrict__ scattering,
                               int* __restrict__ cursor, int2* __restrict__ mdarr) {
    int e = blockIdx.x * blockDim.x + threadIdx.x;
    if (e >= EN) return;
    int p = rid[e];
    float a = absorption[p];
    float s = scattering[p];
    float k = (1.0f - a) * (s * basis[e] + (1.0f - s) * basis[EN + e]);
    int d = delay[e];
    int dpair = (d + 1) >> 1;                       // d in [0,512)
    int off = ((col[e] * SP + PADP - dpair) << 2) | (d & 1);
    int pos = atomicAdd(&cursor[row[e]], 1);
    mdarr[pos] = make_int2(off, __float_as_int(k));
}

// fill per-row pad slots (k=0, safe offset) + global tail pads
__global__ void padfill_kernel(const int* __restrict__ off, const int* __restrict__ cnt,
                               int2* __restrict__ mdarr) {
    int r = blockIdx.x * 256 + threadIdx.x;
    if (r < RN) {
        int n = cnt[r];
        if (n & 1) mdarr[off[r] + n] = make_int2(PADP << 2, 0);
    }
    if (r < 8) mdarr[off[RN] + r] = make_int2(PADP << 2, 0);
}

// ---------------- init: padded cur = half(x * window) ----------------

__global__ __launch_bounds__(256) void init_kernel(const float* __restrict__ x,
                                                   __half* __restrict__ cur) {
    int r = blockIdx.x;
    int tid = threadIdx.x;
    const float* xr = x + r * TN;
    uint* curp = (uint*)cur + (size_t)r * SP;
#pragma unroll
    for (int kk = 0; kk < 3; ++kk) {
        int q = tid + kk * 256;                     // pair index
        int t = q * 2;
        float wa = __expf(LOG_GAMMA * (float)t * INV_SR);
        float wb = __expf(LOG_GAMMA * (float)(t + 1) * INV_SR);
        __half2 h = __float22half2_rn(make_float2(xr[t] * wa, xr[t + 1] * wb));
        uint u = *(uint*)&h;
        curp[PADP + q] = u;
        if (q >= 511) curp[q - 511] = u;            // wrap replica
    }
}

// ---------------- bounce ----------------
// Block = 4 waves; wave w of block handles row rg*4+w, chunk of 256 pairs (4/lane).
// Per edge: ONE global_load_dwordx4 (+1 dword for odd-sample realign).
// 2-edge software pipeline with named A/B register sets; CSR ranges even-padded
// so the loop is branchless. Misaligned multi-dword loads are legal on CDNA
// (UnalignedAccessMode, 4B alignment sufficient).

#define ISSUE(W, X, mo)                                                \
    {                                                                  \
        const uint* rp_ = (const uint*)(curb + (size_t)((mo) & ~1u));  \
        W = *(const uint4*)(rp_ + pb4);                                \
        X = rp_[pb4 + 4];                                              \
    }

#define CONSUME(W, X, mo, kb)                                          \
    {                                                                  \
        float k_ = __uint_as_float((uint)(kb));                        \
        uint v0_, v1_, v2_, v3_;                                       \
        if ((mo) & 1u) {                                               \
            v0_ = __builtin_amdgcn_alignbit(W.y, W.x, 16);             \
            v1_ = __builtin_amdgcn_alignbit(W.z, W.y, 16);             \
            v2_ = __builtin_amdgcn_alignbit(W.w, W.z, 16);             \
            v3_ = __builtin_amdgcn_alignbit(X,   W.w, 16);             \
        } else { v0_ = W.x; v1_ = W.y; v2_ = W.z; v3_ = W.w; }         \
        __half2 h0_ = *(__half2*)&v0_, h1_ = *(__half2*)&v1_;          \
        __half2 h2_ = *(__half2*)&v2_, h3_ = *(__half2*)&v3_;          \
        a0 = fmaf(k_, __half2float(h0_.x), a0);                        \
        a1 = fmaf(k_, __half2float(h0_.y), a1);                        \
        a2 = fmaf(k_, __half2float(h1_.x), a2);                        \
        a3 = fmaf(k_, __half2float(h1_.y), a3);                        \
        a4 = fmaf(k_, __half2float(h2_.x), a4);                        \
        a5 = fmaf(k_, __half2float(h2_.y), a5);                        \
        a6 = fmaf(k_, __half2float(h3_.x), a6);                        \
        a7 = fmaf(k_, __half2float(h3_.y), a7);                        \
    }

__global__ __launch_bounds__(256, 8) void bounce_kernel(
        const __half* __restrict__ cur, __half* __restrict__ nxt,
        const int* __restrict__ offp, const int* __restrict__ cnt,
        const int2* __restrict__ mdarr) {
    int bid = blockIdx.x;
    int rg = bid / 3;
    int chunk = bid - rg * 3;
    int wave = threadIdx.x >> 6;
    int lane = threadIdx.x & 63;
    int r = rg * 4 + wave;
    int c0 = chunk << 8;                            // 0 / 256 / 512
    int pb4 = c0 + (lane << 2);                     // base pair of this lane's 4
    int e0 = rfl(offp[r]);
    int n  = rfl(cnt[r]);
    float a0 = 0.f, a1 = 0.f, a2 = 0.f, a3 = 0.f;
    float a4 = 0.f, a5 = 0.f, a6 = 0.f, a7 = 0.f;
    const char* curb = (const char*)cur;

    if (n > 0) {
        int e1p = e0 + ((n + 1) & ~1);
        uint4 md01 = *(const uint4*)(mdarr + e0);   // e0 even -> 16B aligned
        uint moA = (uint)rfl((int)md01.x), kbA = (uint)rfl((int)md01.y);
        uint moB = (uint)rfl((int)md01.z), kbB = (uint)rfl((int)md01.w);
        uint4 WA, WB; uint XA, XB;
        ISSUE(WA, XA, moA);
        ISSUE(WB, XB, moB);
        for (int j = e0; j + 2 < e1p; j += 2) {
            uint4 mdn = *(const uint4*)(mdarr + j + 2);
            uint moC = (uint)rfl((int)mdn.x), kbC = (uint)rfl((int)mdn.y);
            uint moD = (uint)rfl((int)mdn.z), kbD = (uint)rfl((int)mdn.w);
            CONSUME(WA, XA, moA, kbA); ISSUE(WA, XA, moC);
            CONSUME(WB, XB, moB, kbB); ISSUE(WB, XB, moD);
            moA = moC; kbA = kbC; moB = moD; kbB = kbD;
        }
        CONSUME(WA, XA, moA, kbA);
        CONSUME(WB, XB, moB, kbB);
    }

    __half2 h0 = __float22half2_rn(make_float2(a0, a1));
    __half2 h1 = __float22half2_rn(make_float2(a2, a3));
    __half2 h2 = __float22half2_rn(make_float2(a4, a5));
    __half2 h3 = __float22half2_rn(make_float2(a6, a7));
    uint4 U = make_uint4(*(uint*)&h0, *(uint*)&h1, *(uint*)&h2, *(uint*)&h3);
    uint* nxtp = (uint*)nxt + (size_t)r * SP;
    *(uint4*)(nxtp + PADP + pb4) = U;
    if (c0 == 512) {
        *(uint4*)(nxtp + pb4 - 511) = U;            // full-group wrap replica
    } else if (pb4 == 508) {
        nxtp[0] = U.w;                              // pair q=511 -> slot 0
    }
}

// ---------------- detection (accumulated per bounce, fp32) ----------------

__global__ void detect_kernel(const __half* __restrict__ buf, const float* __restrict__ w,
                              const int* __restrict__ dd, float* __restrict__ det) {
    int t = blockIdx.x * 256 + threadIdx.x;
    int r0 = blockIdx.y * 64;
    float acc = 0.f;
    for (int rr = 0; rr < 64; ++rr) {
        int r = r0 + rr;
        int d = dd[r];
        int s = t - d;
        if (s < 0) s += TN;
        int q = s >> 1;
        acc = fmaf(w[r], __half2float(buf[(size_t)r * (SP * 2) + (PADP + q) * 2 + (s & 1)]), acc);
    }
    atomicAdd(&det[t], acc);
}

__global__ void final_kernel(const float* __restrict__ det, float* __restrict__ out) {
    int t = blockIdx.x * 256 + threadIdx.x;
    if (t < TN) out[t] = det[t] * __expf(-LOG_GAMMA * (float)t * INV_SR);
}

// ---------------- launch ----------------

extern "C" void kernel_launch(void* const* d_in, const int* in_sizes, int n_in,
                              void* d_out, int out_size, void* d_ws, size_t ws_size,
                              hipStream_t stream) {
    const float* init_rad   = (const float*)d_in[0];
    const float* basis      = (const float*)d_in[1];
    const float* absorption = (const float*)d_in[2];
    const float* scattering = (const float*)d_in[3];
    const float* det_w      = (const float*)d_in[4];
    const int*   row        = (const int*)d_in[5];
    const int*   col        = (const int*)d_in[6];
    const int*   rid        = (const int*)d_in[7];
    const int*   delay      = (const int*)d_in[8];
    const int*   det_delay  = (const int*)d_in[9];
    float* out = (float*)d_out;

    char* ws = (char*)d_ws;
    size_t o = 0;
    auto alloc = [&](size_t bytes) {
        void* p = ws + o;
        o = (o + bytes + 255) & ~(size_t)255;
        return p;
    };
    int*    cnt    = (int*)alloc(RN * 4);
    int*    off    = (int*)alloc((RN + 1) * 4);
    int*    cursor = (int*)alloc(RN * 4);
    int2*   mdarr  = (int2*)alloc((size_t)(EN + RN + 8) * 8);
    __half* bufA   = (__half*)alloc((size_t)RN * SP * 4);
    __half* bufB   = (__half*)alloc((size_t)RN * SP * 4);
    float*  det    = (float*)alloc(TN * 4);

    hipMemsetAsync(cnt, 0, RN * 4, stream);
    hipMemsetAsync(det, 0, TN * 4, stream);

    hist_kernel<<<EN / 256, 256, 0, stream>>>(row, cnt);
    scan_kernel<<<1, 1024, 0, stream>>>(cnt, off, cursor);
    scatter_kernel<<<EN / 256, 256, 0, stream>>>(row, col, rid, delay, basis,
                                                 absorption, scattering, cursor, mdarr);
    padfill_kernel<<<RN / 256, 256, 0, stream>>>(off, cnt, mdarr);
    init_kernel<<<RN, 256, 0, stream>>>(init_rad, bufA);

    dim3 dgrid(TN / 256, RN / 64);
    detect_kernel<<<dgrid, 256, 0, stream>>>(bufA, det_w, det_delay, det);

    __half* cur = bufA;
    __half* nxt = bufB;
    for (int b = 0; b < NBOUNCE; ++b) {
        bounce_kernel<<<(RN / 4) * NCHUNK, 256, 0, stream>>>(cur, nxt, off, cnt, mdarr);
        detect_kernel<<<dgrid, 256, 0, stream>>>(nxt, det_w, det_delay, det);
        __half* tmp = cur; cur = nxt; nxt = tmp;
    }

    final_kernel<<<TN / 256, 256, 0, stream>>>(det, out);
}

// Round 7
// 664.460 us; speedup vs baseline: 1.3069x; 1.3069x over previous
//
#include <hip/hip_runtime.h>
#include <hip/hip_bf16.h>
#include <hip/hip_fp16.h>

#define RN 4096
#define EN 131072
#define TN 1536
#define T2 768            // sample-pairs per row
#define SP 1040           // padded row stride in pairs
#define PADP 257          // front wrap-replica pairs
#define PN 256
#define NBOUNCE 12
#define NCHUNK 4          // MUST divide 8 for chunk<->XCD affinity (R6 lesson)
#define CP 192            // pairs per chunk = 64 lanes x 3 pairs
// np.float32(np.log(1e-3))
#define LOG_GAMMA -6.90775528f
#define INV_SR (1.0f / 16000.0f)

#define rfl(x) __builtin_amdgcn_readfirstlane(x)

// ---------------- CSR build ----------------

__global__ void hist_kernel(const int* __restrict__ row, int* __restrict__ cnt) {
    int e = blockIdx.x * blockDim.x + threadIdx.x;
    if (e < EN) atomicAdd(&cnt[row[e]], 1);
}

// single block, 1024 threads: exclusive scan of even-rounded counts.
// Row r's region is [off[r], off[r]+cnt[r]) real + pad slot to even length.
__global__ void scan_kernel(const int* __restrict__ cnt, int* __restrict__ off,
                            int* __restrict__ cursor) {
    __shared__ int part[1024];
    int tid = threadIdx.x;
    int v0 = cnt[tid * 4 + 0], v1 = cnt[tid * 4 + 1];
    int v2 = cnt[tid * 4 + 2], v3 = cnt[tid * 4 + 3];
    int p0 = (v0 + 1) & ~1, p1 = (v1 + 1) & ~1, p2 = (v2 + 1) & ~1, p3 = (v3 + 1) & ~1;
    part[tid] = p0 + p1 + p2 + p3;
    __syncthreads();
    for (int ofs = 1; ofs < 1024; ofs <<= 1) {
        int x = (tid >= ofs) ? part[tid - ofs] : 0;
        __syncthreads();
        part[tid] += x;
        __syncthreads();
    }
    int excl = (tid == 0) ? 0 : part[tid - 1];
    int o0 = excl, o1 = o0 + p0, o2 = o1 + p1, o3 = o2 + p2;
    off[tid * 4 + 0] = o0; cursor[tid * 4 + 0] = o0;
    off[tid * 4 + 1] = o1; cursor[tid * 4 + 1] = o1;
    off[tid * 4 + 2] = o2; cursor[tid * 4 + 2] = o2;
    off[tid * 4 + 3] = o3; cursor[tid * 4 + 3] = o3;
    if (tid == 1023) off[RN] = o3 + p3;
}

// per edge: kernel value + precomputed relative byte offset into the padded layout.
// md.x = ((col*SP + PADP - dpair) << 2) | (delay & 1),  md.y = bits(kern)
__global__ void scatter_kernel(const int* __restrict__ row, const int* __restrict__ col,
                               const int* __restrict__ rid, const int* __restrict__ delay,
                               const float* __restrict__ basis,
                               const float* __restrict__ absorption,
                               const float* __restrict__ scattering,
                               int* __restrict__ cursor, int2* __restrict__ mdarr) {
    int e = blockIdx.x * blockDim.x + threadIdx.x;
    if (e >= EN) return;
    int p = rid[e];
    float a = absorption[p];
    float s = scattering[p];
    float k = (1.0f - a) * (s * basis[e] + (1.0f - s) * basis[EN + e]);
    int d = delay[e];
    int dpair = (d + 1) >> 1;                       // d in [0,512)
    int off = ((col[e] * SP + PADP - dpair) << 2) | (d & 1);
    int pos = atomicAdd(&cursor[row[e]], 1);
    mdarr[pos] = make_int2(off, __float_as_int(k));
}

// fill per-row pad slots (k=0, safe offset) + global tail pads
__global__ void padfill_kernel(const int* __restrict__ off, const int* __restrict__ cnt,
                               int2* __restrict__ mdarr) {
    int r = blockIdx.x * 256 + threadIdx.x;
    if (r < RN) {
        int n = cnt[r];
        if (n & 1) mdarr[off[r] + n] = make_int2(PADP << 2, 0);
    }
    if (r < 8) mdarr[off[RN] + r] = make_int2(PADP << 2, 0);
}

// ---------------- init: padded cur = half(x * window) ----------------

__global__ __launch_bounds__(256) void init_kernel(const float* __restrict__ x,
                                                   __half* __restrict__ cur) {
    int r = blockIdx.x;
    int tid = threadIdx.x;
    const float* xr = x + r * TN;
    uint* curp = (uint*)cur + (size_t)r * SP;
#pragma unroll
    for (int kk = 0; kk < 3; ++kk) {
        int q = tid + kk * 256;                     // pair index
        int t = q * 2;
        float wa = __expf(LOG_GAMMA * (float)t * INV_SR);
        float wb = __expf(LOG_GAMMA * (float)(t + 1) * INV_SR);
        __half2 h = __float22half2_rn(make_float2(xr[t] * wa, xr[t + 1] * wb));
        uint u = *(uint*)&h;
        curp[PADP + q] = u;
        if (q >= 511) curp[q - 511] = u;            // wrap replica
    }
}

// ---------------- bounce ----------------
// Block = 2 waves; wave w handles row rg*2+w, chunk of 192 pairs, 3 contiguous
// pairs per lane. bid = rg*4 + chunk, NCHUNK=4 | 8 -> chunk c lands only on
// XCDs {c, c+4} (round-robin dispatch) => per-XCD source window is 449 of 1025
// pairs per row (L2 locality; R4 proved ~115 MB vs 168 MB without affinity).
// Per edge per lane: ONE global_load_dwordx4 covers 3 pairs + realign dword.
// 2-edge software pipeline (A/B register sets), branchless even-padded CSR.

#define ISSUE(W, mo)                                                   \
    {                                                                  \
        const uint* rp_ = (const uint*)(curb + (size_t)((mo) & ~1u));  \
        W = *(const uint4*)(rp_ + pb);                                 \
    }

#define CONSUME(W, mo, kb)                                             \
    {                                                                  \
        float k_ = __uint_as_float((uint)(kb));                        \
        uint v0_, v1_, v2_;                                            \
        if ((mo) & 1u) {                                               \
            v0_ = __builtin_amdgcn_alignbit(W.y, W.x, 16);             \
            v1_ = __builtin_amdgcn_alignbit(W.z, W.y, 16);             \
            v2_ = __builtin_amdgcn_alignbit(W.w, W.z, 16);             \
        } else { v0_ = W.x; v1_ = W.y; v2_ = W.z; }                    \
        __half2 h0_ = *(__half2*)&v0_;                                 \
        __half2 h1_ = *(__half2*)&v1_;                                 \
        __half2 h2_ = *(__half2*)&v2_;                                 \
        a0 = fmaf(k_, __half2float(h0_.x), a0);                        \
        a1 = fmaf(k_, __half2float(h0_.y), a1);                        \
        a2 = fmaf(k_, __half2float(h1_.x), a2);                        \
        a3 = fmaf(k_, __half2float(h1_.y), a3);                        \
        a4 = fmaf(k_, __half2float(h2_.x), a4);                        \
        a5 = fmaf(k_, __half2float(h2_.y), a5);                        \
    }

__global__ __launch_bounds__(128, 8) void bounce_kernel(
        const __half* __restrict__ cur, __half* __restrict__ nxt,
        const int* __restrict__ offp, const int* __restrict__ cnt,
        const int2* __restrict__ mdarr) {
    int bid = blockIdx.x;
    int rg = bid >> 2;
    int chunk = bid & 3;
    int wave = threadIdx.x >> 6;
    int lane = threadIdx.x & 63;
    int r = rg * 2 + wave;
    int c0 = chunk * CP;
    int pb = c0 + lane * 3;                         // base pair of this lane's 3
    int e0 = rfl(offp[r]);
    int n  = rfl(cnt[r]);
    float a0 = 0.f, a1 = 0.f, a2 = 0.f, a3 = 0.f, a4 = 0.f, a5 = 0.f;
    const char* curb = (const char*)cur;

    if (n > 0) {
        int e1p = e0 + ((n + 1) & ~1);
        uint4 md01 = *(const uint4*)(mdarr + e0);   // e0 even -> 16B aligned
        uint moA = (uint)rfl((int)md01.x), kbA = (uint)rfl((int)md01.y);
        uint moB = (uint)rfl((int)md01.z), kbB = (uint)rfl((int)md01.w);
        uint4 WA, WB;
        ISSUE(WA, moA);
        ISSUE(WB, moB);
        for (int j = e0 + 2; j < e1p; j += 2) {
            uint4 mdn = *(const uint4*)(mdarr + j);
            uint moC = (uint)rfl((int)mdn.x), kbC = (uint)rfl((int)mdn.y);
            uint moD = (uint)rfl((int)mdn.z), kbD = (uint)rfl((int)mdn.w);
            CONSUME(WA, moA, kbA); ISSUE(WA, moC);
            CONSUME(WB, moB, kbB); ISSUE(WB, moD);
            moA = moC; kbA = kbC; moB = moD; kbB = kbD;
        }
        CONSUME(WA, moA, kbA);
        CONSUME(WB, moB, kbB);
    }

    __half2 h0 = __float22half2_rn(make_float2(a0, a1));
    __half2 h1 = __float22half2_rn(make_float2(a2, a3));
    __half2 h2 = __float22half2_rn(make_float2(a4, a5));
    uint u0 = *(uint*)&h0, u1 = *(uint*)&h1, u2 = *(uint*)&h2;
    uint* nxtp = (uint*)nxt + (size_t)r * SP;
    nxtp[PADP + pb]     = u0;
    nxtp[PADP + pb + 1] = u1;
    nxtp[PADP + pb + 2] = u2;
    if (pb + 2 >= 511) {                            // wrap replica writes
        if (pb     >= 511) nxtp[pb - 511] = u0;
        if (pb + 1 >= 511) nxtp[pb - 510] = u1;
        nxtp[pb - 509] = u2;
    }
}

// ---------------- detection (accumulated per bounce, fp32) ----------------

__global__ __launch_bounds__(256) void detect_kernel(
        const __half* __restrict__ buf, const float* __restrict__ w,
        const int* __restrict__ dd, float* __restrict__ det) {
    int t = blockIdx.x * 256 + threadIdx.x;
    int r0 = blockIdx.y * 16;
    float acc = 0.f;
#pragma unroll 4
    for (int rr = 0; rr < 16; ++rr) {
        int r = r0 + rr;
        int d = dd[r];
        int s = t - d;
        if (s < 0) s += TN;
        int q = s >> 1;
        acc = fmaf(w[r], __half2float(buf[(size_t)r * (SP * 2) + (PADP + q) * 2 + (s & 1)]), acc);
    }
    atomicAdd(&det[t], acc);
}

__global__ void final_kernel(const float* __restrict__ det, float* __restrict__ out) {
    int t = blockIdx.x * 256 + threadIdx.x;
    if (t < TN) out[t] = det[t] * __expf(-LOG_GAMMA * (float)t * INV_SR);
}

// ---------------- launch ----------------

extern "C" void kernel_launch(void* const* d_in, const int* in_sizes, int n_in,
                              void* d_out, int out_size, void* d_ws, size_t ws_size,
                              hipStream_t stream) {
    const float* init_rad   = (const float*)d_in[0];
    const float* basis      = (const float*)d_in[1];
    const float* absorption = (const float*)d_in[2];
    const float* scattering = (const float*)d_in[3];
    const float* det_w      = (const float*)d_in[4];
    const int*   row        = (const int*)d_in[5];
    const int*   col        = (const int*)d_in[6];
    const int*   rid        = (const int*)d_in[7];
    const int*   delay      = (const int*)d_in[8];
    const int*   det_delay  = (const int*)d_in[9];
    float* out = (float*)d_out;

    char* ws = (char*)d_ws;
    size_t o = 0;
    auto alloc = [&](size_t bytes) {
        void* p = ws + o;
        o = (o + bytes + 255) & ~(size_t)255;
        return p;
    };
    int*    cnt    = (int*)alloc(RN * 4);
    int*    off    = (int*)alloc((RN + 1) * 4);
    int*    cursor = (int*)alloc(RN * 4);
    int2*   mdarr  = (int2*)alloc((size_t)(EN + RN + 8) * 8);
    __half* bufA   = (__half*)alloc((size_t)RN * SP * 4);
    __half* bufB   = (__half*)alloc((size_t)RN * SP * 4);
    float*  det    = (float*)alloc(TN * 4);

    hipMemsetAsync(cnt, 0, RN * 4, stream);
    hipMemsetAsync(det, 0, TN * 4, stream);

    hist_kernel<<<EN / 256, 256, 0, stream>>>(row, cnt);
    scan_kernel<<<1, 1024, 0, stream>>>(cnt, off, cursor);
    scatter_kernel<<<EN / 256, 256, 0, stream>>>(row, col, rid, delay, basis,
                                                 absorption, scattering, cursor, mdarr);
    padfill_kernel<<<RN / 256, 256, 0, stream>>>(off, cnt, mdarr);
    init_kernel<<<RN, 256, 0, stream>>>(init_rad, bufA);

    dim3 dgrid(TN / 256, RN / 16);
    detect_kernel<<<dgrid, 256, 0, stream>>>(bufA, det_w, det_delay, det);

    __half* cur = bufA;
    __half* nxt = bufB;
    for (int b = 0; b < NBOUNCE; ++b) {
        bounce_kernel<<<(RN / 2) * NCHUNK, 128, 0, stream>>>(cur, nxt, off, cnt, mdarr);
        detect_kernel<<<dgrid, 256, 0, stream>>>(nxt, det_w, det_delay, det);
        __half* tmp = cur; cur = nxt; nxt = tmp;
    }

    final_kernel<<<TN / 256, 256, 0, stream>>>(det, out);
}

// Round 9
// 627.405 us; speedup vs baseline: 1.3841x; 1.0591x over previous
//
#include <hip/hip_runtime.h>
#include <hip/hip_bf16.h>
#include <hip/hip_fp16.h>

#define RN 4096
#define EN 131072
#define TN 1536
#define T2 768            // sample-pairs per row
#define SP 1040           // padded row stride in pairs
#define PADP 257          // front wrap-replica pairs
#define PN 256
#define NBOUNCE 12
#define NCHUNK 4          // chunk c -> XCDs {c, c+4} (R4/R7 validated)
#define CP 192            // pairs per chunk = 64 lanes x 3 pairs
// np.float32(np.log(1e-3))
#define LOG_GAMMA -6.90775528f
#define INV_SR (1.0f / 16000.0f)

#define rfl(x) __builtin_amdgcn_readfirstlane(x)

// ---------------- CSR build (edges ordered by source-col half within each row) --

// cnt2[2r] = #edges of row r with col<2048, cnt2[2r+1] = #edges with col>=2048
__global__ void hist_kernel(const int* __restrict__ row, const int* __restrict__ col,
                            int* __restrict__ cnt2) {
    int e = blockIdx.x * blockDim.x + threadIdx.x;
    if (e < EN) atomicAdd(&cnt2[row[e] * 2 + (col[e] >> 11)], 1);
}

// single block, 1024 threads: exclusive scan of even-rounded row totals.
// Row region = [off[r], off[r]+n) real (lo-half edges first) + pad to even.
__global__ void scan_kernel(const int* __restrict__ cnt2, int* __restrict__ off,
                            int* __restrict__ cursor2, int* __restrict__ ntot) {
    __shared__ int part[1024];
    int tid = threadIdx.x;
    int l0 = cnt2[(tid * 4 + 0) * 2], h0 = cnt2[(tid * 4 + 0) * 2 + 1];
    int l1 = cnt2[(tid * 4 + 1) * 2], h1 = cnt2[(tid * 4 + 1) * 2 + 1];
    int l2 = cnt2[(tid * 4 + 2) * 2], h2 = cnt2[(tid * 4 + 2) * 2 + 1];
    int l3 = cnt2[(tid * 4 + 3) * 2], h3 = cnt2[(tid * 4 + 3) * 2 + 1];
    int n0 = l0 + h0, n1 = l1 + h1, n2 = l2 + h2, n3 = l3 + h3;
    int p0 = (n0 + 1) & ~1, p1 = (n1 + 1) & ~1, p2 = (n2 + 1) & ~1, p3 = (n3 + 1) & ~1;
    part[tid] = p0 + p1 + p2 + p3;
    __syncthreads();
    for (int ofs = 1; ofs < 1024; ofs <<= 1) {
        int x = (tid >= ofs) ? part[tid - ofs] : 0;
        __syncthreads();
        part[tid] += x;
        __syncthreads();
    }
    int excl = (tid == 0) ? 0 : part[tid - 1];
    int o0 = excl, o1 = o0 + p0, o2 = o1 + p1, o3 = o2 + p2;
    int r0 = tid * 4;
    off[r0 + 0] = o0; cursor2[(r0 + 0) * 2] = o0; cursor2[(r0 + 0) * 2 + 1] = o0 + l0; ntot[r0 + 0] = n0;
    off[r0 + 1] = o1; cursor2[(r0 + 1) * 2] = o1; cursor2[(r0 + 1) * 2 + 1] = o1 + l1; ntot[r0 + 1] = n1;
    off[r0 + 2] = o2; cursor2[(r0 + 2) * 2] = o2; cursor2[(r0 + 2) * 2 + 1] = o2 + l2; ntot[r0 + 2] = n2;
    off[r0 + 3] = o3; cursor2[(r0 + 3) * 2] = o3; cursor2[(r0 + 3) * 2 + 1] = o3 + l3; ntot[r0 + 3] = n3;
    if (tid == 1023) off[RN] = o3 + p3;
}

// per edge: kernel value + precomputed relative byte offset into the padded layout.
// md.x = ((col*SP + PADP - dpair) << 2) | (delay & 1),  md.y = bits(kern)
// Placed lo-col-half first within the row region (time-phased L2 blocking).
__global__ void scatter_kernel(const int* __restrict__ row, const int* __restrict__ col,
                               const int* __restrict__ rid, const int* __restrict__ delay,
                               const float* __restrict__ basis,
                               const float* __restrict__ absorption,
                               const float* __restrict__ scattering,
                               int* __restrict__ cursor2, int2* __restrict__ mdarr) {
    int e = blockIdx.x * blockDim.x + threadIdx.x;
    if (e >= EN) return;
    int p = rid[e];
    float a = absorption[p];
    float s = scattering[p];
    float k = (1.0f - a) * (s * basis[e] + (1.0f - s) * basis[EN + e]);
    int d = delay[e];
    int c = col[e];
    int dpair = (d + 1) >> 1;                       // d in [0,512)
    int o = ((c * SP + PADP - dpair) << 2) | (d & 1);
    int pos = atomicAdd(&cursor2[row[e] * 2 + (c >> 11)], 1);
    mdarr[pos] = make_int2(o, __float_as_int(k));
}

// fill per-row pad slots (k=0, safe offset) + global tail pads
__global__ void padfill_kernel(const int* __restrict__ off, const int* __restrict__ ntot,
                               int2* __restrict__ mdarr) {
    int r = blockIdx.x * 256 + threadIdx.x;
    if (r < RN) {
        int n = ntot[r];
        if (n & 1) mdarr[off[r] + n] = make_int2(PADP << 2, 0);
    }
    if (r < 8) mdarr[off[RN] + r] = make_int2(PADP << 2, 0);
}

// ---------------- init: padded cur = half(x * window) ----------------

__global__ __launch_bounds__(256) void init_kernel(const float* __restrict__ x,
                                                   __half* __restrict__ cur) {
    int r = blockIdx.x;
    int tid = threadIdx.x;
    const float* xr = x + r * TN;
    uint* curp = (uint*)cur + (size_t)r * SP;
#pragma unroll
    for (int kk = 0; kk < 3; ++kk) {
        int q = tid + kk * 256;                     // pair index
        int t = q * 2;
        float wa = __expf(LOG_GAMMA * (float)t * INV_SR);
        float wb = __expf(LOG_GAMMA * (float)(t + 1) * INV_SR);
        __half2 h = __float22half2_rn(make_float2(xr[t] * wa, xr[t + 1] * wb));
        uint u = *(uint*)&h;
        curp[PADP + q] = u;
        if (q >= 511) curp[q - 511] = u;            // wrap replica
    }
}

// ---------------- bounce (EXACT R7 structure — validated end-to-end) ----------
// Block = 2 waves; wave w handles row rg*2+w, chunk of 192 pairs, 3 contiguous
// pairs per lane. bid = rg*4 + chunk -> chunk c lands only on XCDs {c, c+4}.
// Per edge per lane: ONE global_load_dwordx4 covers 3 pairs + realign dword.
// 2-edge software pipeline (A/B register sets), branchless even-padded CSR.
// Edge order within a row: col<2048 first -> all blocks sweep source rows
// 0..2047 then 2048..4095 => instantaneous per-XCD L2 set ~3.7 MB (fits 4 MB).

#define ISSUE(W, mo)                                                   \
    {                                                                  \
        const uint* rp_ = (const uint*)(curb + (size_t)((mo) & ~1u));  \
        W = *(const uint4*)(rp_ + pb);                                 \
    }

#define CONSUME(W, mo, kb)                                             \
    {                                                                  \
        float k_ = __uint_as_float((uint)(kb));                        \
        uint v0_, v1_, v2_;                                            \
        if ((mo) & 1u) {                                               \
            v0_ = __builtin_amdgcn_alignbit(W.y, W.x, 16);             \
            v1_ = __builtin_amdgcn_alignbit(W.z, W.y, 16);             \
            v2_ = __builtin_amdgcn_alignbit(W.w, W.z, 16);             \
        } else { v0_ = W.x; v1_ = W.y; v2_ = W.z; }                    \
        __half2 h0_ = *(__half2*)&v0_;                                 \
        __half2 h1_ = *(__half2*)&v1_;                                 \
        __half2 h2_ = *(__half2*)&v2_;                                 \
        a0 = fmaf(k_, __half2float(h0_.x), a0);                        \
        a1 = fmaf(k_, __half2float(h0_.y), a1);                        \
        a2 = fmaf(k_, __half2float(h1_.x), a2);                        \
        a3 = fmaf(k_, __half2float(h1_.y), a3);                        \
        a4 = fmaf(k_, __half2float(h2_.x), a4);                        \
        a5 = fmaf(k_, __half2float(h2_.y), a5);                        \
    }

__global__ __launch_bounds__(128, 8) void bounce_kernel(
        const __half* __restrict__ cur, __half* __restrict__ nxt,
        const int* __restrict__ offp, const int* __restrict__ ntot,
        const int2* __restrict__ mdarr) {
    int bid = blockIdx.x;
    int rg = bid >> 2;
    int chunk = bid & 3;
    int wave = threadIdx.x >> 6;
    int lane = threadIdx.x & 63;
    int r = rg * 2 + wave;
    int c0 = chunk * CP;
    int pb = c0 + lane * 3;                         // base pair of this lane's 3
    int e0 = rfl(offp[r]);
    int n  = rfl(ntot[r]);
    float a0 = 0.f, a1 = 0.f, a2 = 0.f, a3 = 0.f, a4 = 0.f, a5 = 0.f;
    const char* curb = (const char*)cur;

    if (n > 0) {
        int e1p = e0 + ((n + 1) & ~1);
        uint4 md01 = *(const uint4*)(mdarr + e0);   // e0 even -> 16B aligned
        uint moA = (uint)rfl((int)md01.x), kbA = (uint)rfl((int)md01.y);
        uint moB = (uint)rfl((int)md01.z), kbB = (uint)rfl((int)md01.w);
        uint4 WA, WB;
        ISSUE(WA, moA);
        ISSUE(WB, moB);
        for (int j = e0 + 2; j < e1p; j += 2) {
            uint4 mdn = *(const uint4*)(mdarr + j);
            uint moC = (uint)rfl((int)mdn.x), kbC = (uint)rfl((int)mdn.y);
            uint moD = (uint)rfl((int)mdn.z), kbD = (uint)rfl((int)mdn.w);
            CONSUME(WA, moA, kbA); ISSUE(WA, moC);
            CONSUME(WB, moB, kbB); ISSUE(WB, moD);
            moA = moC; kbA = kbC; moB = moD; kbB = kbD;
        }
        CONSUME(WA, moA, kbA);
        CONSUME(WB, moB, kbB);
    }

    __half2 h0 = __float22half2_rn(make_float2(a0, a1));
    __half2 h1 = __float22half2_rn(make_float2(a2, a3));
    __half2 h2 = __float22half2_rn(make_float2(a4, a5));
    uint u0 = *(uint*)&h0, u1 = *(uint*)&h1, u2 = *(uint*)&h2;
    uint* nxtp = (uint*)nxt + (size_t)r * SP;
    nxtp[PADP + pb]     = u0;
    nxtp[PADP + pb + 1] = u1;
    nxtp[PADP + pb + 2] = u2;
    if (pb + 2 >= 511) {                            // wrap replica writes
        if (pb     >= 511) nxtp[pb - 511] = u0;
        if (pb + 1 >= 511) nxtp[pb - 510] = u1;
        nxtp[pb - 509] = u2;
    }
}

// ---------------- detection (accumulated per bounce, fp32) ----------------
// grid (4 chunks of 384 t, 256 row-groups of 16); linear bid = cx + 4*ry ->
// XCD = cx + 4*(ry&1): chunk cx reads samples chunk cx just wrote on the SAME
// XCD pair {cx, cx+4} as bounce (L2-warm). 3 t per thread for MLP.

__global__ __launch_bounds__(128) void detect_kernel(
        const __half* __restrict__ buf, const float* __restrict__ w,
        const int* __restrict__ dd, float* __restrict__ det) {
    int cx = blockIdx.x;
    int r0 = blockIdx.y * 16;
    int tid = threadIdx.x;
    int tb = cx * 384 + tid;
    float acc0 = 0.f, acc1 = 0.f, acc2 = 0.f;
#pragma unroll 4
    for (int rr = 0; rr < 16; ++rr) {
        int r = r0 + rr;
        int d = dd[r];
        float wr = w[r];
        const __half* bufr = buf + (size_t)r * (SP * 2);
        int s0 = tb - d;           if (s0 < 0) s0 += TN;
        int s1 = tb + 128 - d;     if (s1 < 0) s1 += TN;
        int s2 = tb + 256 - d;     if (s2 < 0) s2 += TN;
        acc0 = fmaf(wr, __half2float(bufr[(PADP + (s0 >> 1)) * 2 + (s0 & 1)]), acc0);
        acc1 = fmaf(wr, __half2float(bufr[(PADP + (s1 >> 1)) * 2 + (s1 & 1)]), acc1);
        acc2 = fmaf(wr, __half2float(bufr[(PADP + (s2 >> 1)) * 2 + (s2 & 1)]), acc2);
    }
    atomicAdd(&det[tb], acc0);
    atomicAdd(&det[tb + 128], acc1);
    atomicAdd(&det[tb + 256], acc2);
}

__global__ void final_kernel(const float* __restrict__ det, float* __restrict__ out) {
    int t = blockIdx.x * 256 + threadIdx.x;
    if (t < TN) out[t] = det[t] * __expf(-LOG_GAMMA * (float)t * INV_SR);
}

// ---------------- launch ----------------

extern "C" void kernel_launch(void* const* d_in, const int* in_sizes, int n_in,
                              void* d_out, int out_size, void* d_ws, size_t ws_size,
                              hipStream_t stream) {
    const float* init_rad   = (const float*)d_in[0];
    const float* basis      = (const float*)d_in[1];
    const float* absorption = (const float*)d_in[2];
    const float* scattering = (const float*)d_in[3];
    const float* det_w      = (const float*)d_in[4];
    const int*   row        = (const int*)d_in[5];
    const int*   col        = (const int*)d_in[6];
    const int*   rid        = (const int*)d_in[7];
    const int*   delay      = (const int*)d_in[8];
    const int*   det_delay  = (const int*)d_in[9];
    float* out = (float*)d_out;

    char* ws = (char*)d_ws;
    size_t o = 0;
    auto alloc = [&](size_t bytes) {
        void* p = ws + o;
        o = (o + bytes + 255) & ~(size_t)255;
        return p;
    };
    int*    cnt2    = (int*)alloc(RN * 2 * 4);
    int*    off     = (int*)alloc((RN + 1) * 4);
    int*    cursor2 = (int*)alloc(RN * 2 * 4);
    int*    ntot    = (int*)alloc(RN * 4);
    int2*   mdarr   = (int2*)alloc((size_t)(EN + RN + 8) * 8);
    __half* bufA    = (__half*)alloc((size_t)RN * SP * 4);
    __half* bufB    = (__half*)alloc((size_t)RN * SP * 4);
    float*  det     = (float*)alloc(TN * 4);

    hipMemsetAsync(cnt2, 0, RN * 2 * 4, stream);
    hipMemsetAsync(det, 0, TN * 4, stream);

    hist_kernel<<<EN / 256, 256, 0, stream>>>(row, col, cnt2);
    scan_kernel<<<1, 1024, 0, stream>>>(cnt2, off, cursor2, ntot);
    scatter_kernel<<<EN / 256, 256, 0, stream>>>(row, col, rid, delay, basis,
                                                 absorption, scattering, cursor2, mdarr);
    padfill_kernel<<<RN / 256, 256, 0, stream>>>(off, ntot, mdarr);
    init_kernel<<<RN, 256, 0, stream>>>(init_rad, bufA);

    dim3 dgrid(NCHUNK, RN / 16);
    detect_kernel<<<dgrid, 128, 0, stream>>>(bufA, det_w, det_delay, det);

    __half* cur = bufA;
    __half* nxt = bufB;
    for (int b = 0; b < NBOUNCE; ++b) {
        bounce_kernel<<<(RN / 2) * NCHUNK, 128, 0, stream>>>(cur, nxt, off, ntot, mdarr);
        detect_kernel<<<dgrid, 128, 0, stream>>>(nxt, det_w, det_delay, det);
        __half* tmp = cur; cur = nxt; nxt = tmp;
    }

    final_kernel<<<TN / 256, 256, 0, stream>>>(det, out);
}